// Round 2
// baseline (449.688 us; speedup 1.0000x reference)
//
#include <hip/hip_runtime.h>

#define DD 512
#define DKk 100
#define NT 7          // ceil(100/16) column tiles
#define CHUNK 16
#define MAXN 208      // max padded N (200 -> 13 chunks * 16)
#define LDS_STRIDE 520  // shorts per staged row (+8 pad)

typedef __attribute__((ext_vector_type(8))) short short8;
typedef __attribute__((ext_vector_type(4))) float f32x4;

struct AttendArgs {
  const float* feats[4];
  const float* wfeat[4];
  const float* wf[4];
  const float* bias[4];
  int   N[4];
  float coef[4];
};

// fp32 -> bf16 bits, round-to-nearest-even
__device__ __forceinline__ short f2bf(float x) {
  unsigned u = __builtin_bit_cast(unsigned, x);
  unsigned r = (u + 0x7fffu + ((u >> 16) & 1u)) >> 16;
  return (short)r;
}
__device__ __forceinline__ float bf2f(unsigned short s) {
  unsigned u = ((unsigned)s) << 16;
  return __builtin_bit_cast(float, u);
}
__device__ __forceinline__ float fast_tanh(float x) {
  const float e = __expf(2.0f * x);
  return 1.0f - 2.0f / (e + 1.0f);
}

// VALU cross-lane add via DPP (replaces ds_swizzle shuffles; row=16 lanes = one
// q-group). Sequence xor1, xor2, half_mirror, mirror = full 16-lane sum.
#define DPP_ADD(x, CTRL)                                                      \
  (x) += __builtin_bit_cast(float, __builtin_amdgcn_update_dpp(               \
             0, __builtin_bit_cast(int, (x)), (CTRL), 0xF, 0xF, true))

// ---------------------------------------------------------------------------
// Fused per-(a,b) kernel, R2 of this session.
// launch_bounds(512,4): force unified VGPR+AGPR <= 128/wave so 2 blocks/CU
// co-reside (R1's 68 VGPR + 64 AGPR bfrag = 132 dropped us to 1 block/CU).
// Loop per chunk (2 barriers): stage(c) -> prefetch(c+1) -> B1 ->
//   [waves 0-6: MFMA(c) + tanh + DPP-reduce -> sc2(c)]
//   [all waves: accum(c-1) from other LDS buffer into pA/pB + online den]
// -> B2.
// DS diet vs R1: partial 16-way-conflict LDS accumulator -> pA/pB split
// (conflict-free b128); shfl_xor (DS pipe) -> DPP (VALU); score reads 16xb32
// -> 4 broadcast b128 via sc2[n][8] transpose; staging 4x8B -> 2x16B writes.
// wprep kernel deleted: bfrag built in prologue directly from global w
// (16-float segments, dense coalescing, L2-hot, ~2us).
// Softmax: scores bounded (|s|<~8) => no max pass; padded rows get
// sc2[n][7] = -1e30 so exp -> 0 exactly (keeps online denominator correct).
// ---------------------------------------------------------------------------
__global__ __launch_bounds__(512, 4)
void fused_kernel(AttendArgs args, float* __restrict__ out) {
  const int a = blockIdx.x & 3;        // interleave a for load balance
  const int b = blockIdx.x >> 2;
  const int tid = threadIdx.x;
  const int lane = tid & 63;
  const int wave = tid >> 6;           // col tile t (0..6 MFMA; all 8 accum)
  const int m = lane & 15;
  const int q = lane >> 4;
  const int N = args.N[a];
  const float* __restrict__ feats = args.feats[a] + (size_t)b * (size_t)N * DD;

  __shared__ __align__(16) unsigned short f_lds[2][CHUNK][LDS_STRIDE]; // 33,280
  __shared__ __align__(16) float sc2[MAXN][8];                         //  6,656
  __shared__ __align__(16) float pA[8][256];                           //  8,192
  __shared__ __align__(16) float pB[8][256];                           //  8,192
  __shared__ float den8[8];
  // total 56,352 B -> 2 blocks/CU (112,704 <= 160 KiB), static <= 64 KiB.

  // --- B fragments direct from global w (row-major [512][100]) -------------
  // bfrag[ks][j] = bf16(w[ks*32+q*8+j][wave*16+m]); per-instr: 16 consecutive
  // floats per 16-lane group = 4 dense 64B segments. L2-resident (w = 200KB).
  short8 bfrag[16];
  float wfv = 0.f;
  {
    const int col = wave * 16 + m;
    const bool ok = (wave < NT) && (col < DKk);
    if (ok) wfv = args.wf[a][col];
    const float* __restrict__ wp = args.wfeat[a] + col;
    #pragma unroll
    for (int ks = 0; ks < 16; ++ks) {
      short8 v;
      #pragma unroll
      for (int j = 0; j < 8; ++j)
        v[j] = ok ? f2bf(wp[(size_t)(ks * 32 + q * 8 + j) * DKk]) : (short)0;
      bfrag[ks] = v;
    }
  }

  // bias in score slot 7; -1e30 sentinel kills padded rows in exp()
  if (tid < MAXN) sc2[tid][7] = (tid < N) ? args.bias[a][tid] : -1e30f;
  {
    const f32x4 z = {0.f, 0.f, 0.f, 0.f};
    *reinterpret_cast<f32x4*>(&pA[wave][lane * 4]) = z;
    *reinterpret_cast<f32x4*>(&pB[wave][lane * 4]) = z;
  }

  const int nchunks = (N + CHUNK - 1) / CHUNK;
  float den = 0.f;

  // accumulate chunk at rows [n0, n0+16) staged in f_lds[pb].
  // Thread (wave, lane) owns cols [lane*8, lane*8+8), rows {wave, wave+8}.
  // Padded rows: e = exp(-1e30) = 0 and staged feats are 0 -> no-op.
  auto accum = [&](int pb, int n0) {
    const int n1 = n0 + wave, n2 = n0 + wave + 8;
    const f32x4 sa1 = *reinterpret_cast<const f32x4*>(&sc2[n1][0]);
    const f32x4 sb1 = *reinterpret_cast<const f32x4*>(&sc2[n1][4]);
    const f32x4 sa2 = *reinterpret_cast<const f32x4*>(&sc2[n2][0]);
    const f32x4 sb2 = *reinterpret_cast<const f32x4*>(&sc2[n2][4]);
    const float e1 = __expf(sa1[0] + sa1[1] + sa1[2] + sa1[3] +
                            sb1[0] + sb1[1] + sb1[2] + sb1[3]);
    const float e2 = __expf(sa2[0] + sa2[1] + sa2[2] + sa2[3] +
                            sb2[0] + sb2[1] + sb2[2] + sb2[3]);
    den += e1 + e2;
    const short8 f1 = *reinterpret_cast<const short8*>(&f_lds[pb][wave][lane * 8]);
    const short8 f2 = *reinterpret_cast<const short8*>(&f_lds[pb][wave + 8][lane * 8]);
    f32x4 lo = *reinterpret_cast<const f32x4*>(&pA[wave][lane * 4]);
    f32x4 hi = *reinterpret_cast<const f32x4*>(&pB[wave][lane * 4]);
    #pragma unroll
    for (int j = 0; j < 4; ++j) {
      lo[j] = fmaf(e1, bf2f((unsigned short)f1[j]),
              fmaf(e2, bf2f((unsigned short)f2[j]), lo[j]));
      hi[j] = fmaf(e1, bf2f((unsigned short)f1[j + 4]),
              fmaf(e2, bf2f((unsigned short)f2[j + 4]), hi[j]));
    }
    *reinterpret_cast<f32x4*>(&pA[wave][lane * 4]) = lo;
    *reinterpret_cast<f32x4*>(&pB[wave][lane * 4]) = hi;
  };

  // --- prefetch chunk 0: thread loads rows {wave, wave+8}, 32B each ---------
  float4 pf[4];
  #pragma unroll
  for (int h = 0; h < 2; ++h) {
    const int row = wave + h * 8;
    const float* src = feats + (size_t)row * DD + lane * 8;
    const bool ok = row < N;
    pf[2 * h]     = ok ? *reinterpret_cast<const float4*>(src)     : make_float4(0.f, 0.f, 0.f, 0.f);
    pf[2 * h + 1] = ok ? *reinterpret_cast<const float4*>(src + 4) : make_float4(0.f, 0.f, 0.f, 0.f);
  }

  for (int c = 0; c < nchunks; ++c) {
    const int bufc = c & 1;
    // stage regs (chunk c) -> bf16 LDS, one 16B write per row-half
    #pragma unroll
    for (int h = 0; h < 2; ++h) {
      const float4 va = pf[2 * h], vb = pf[2 * h + 1];
      short8 pk = { f2bf(va.x), f2bf(va.y), f2bf(va.z), f2bf(va.w),
                    f2bf(vb.x), f2bf(vb.y), f2bf(vb.z), f2bf(vb.w) };
      *reinterpret_cast<short8*>(&f_lds[bufc][wave + h * 8][lane * 8]) = pk;
    }
    // issue prefetch of chunk c+1 (stays in flight across B1+compute+B2)
    if (c + 1 < nchunks) {
      const int n0n = (c + 1) * CHUNK;
      #pragma unroll
      for (int h = 0; h < 2; ++h) {
        const int row = n0n + wave + h * 8;
        const float* src = feats + (size_t)row * DD + lane * 8;
        const bool ok = row < N;
        pf[2 * h]     = ok ? *reinterpret_cast<const float4*>(src)     : make_float4(0.f, 0.f, 0.f, 0.f);
        pf[2 * h + 1] = ok ? *reinterpret_cast<const float4*>(src + 4) : make_float4(0.f, 0.f, 0.f, 0.f);
      }
    }
    __syncthreads();  // B1: staging of c visible

    if (wave < NT) {
      f32x4 acc = {0.f, 0.f, 0.f, 0.f};
      #pragma unroll
      for (int ks = 0; ks < 16; ++ks) {
        const short8 af = *reinterpret_cast<const short8*>(&f_lds[bufc][m][ks * 32 + q * 8]);
        acc = __builtin_amdgcn_mfma_f32_16x16x32_bf16(af, bfrag[ks], acc, 0, 0, 0);
      }
      float p0 = fast_tanh(acc[0]) * wfv;
      float p1 = fast_tanh(acc[1]) * wfv;
      float p2 = fast_tanh(acc[2]) * wfv;
      float p3 = fast_tanh(acc[3]) * wfv;
      DPP_ADD(p0, 0xB1);  DPP_ADD(p1, 0xB1);  DPP_ADD(p2, 0xB1);  DPP_ADD(p3, 0xB1);
      DPP_ADD(p0, 0x4E);  DPP_ADD(p1, 0x4E);  DPP_ADD(p2, 0x4E);  DPP_ADD(p3, 0x4E);
      DPP_ADD(p0, 0x141); DPP_ADD(p1, 0x141); DPP_ADD(p2, 0x141); DPP_ADD(p3, 0x141);
      DPP_ADD(p0, 0x140); DPP_ADD(p1, 0x140); DPP_ADD(p2, 0x140); DPP_ADD(p3, 0x140);
      // lanes m=0..3 write rows q*4+m (select chain keeps indices static)
      float pv = p0;
      pv = (m == 1) ? p1 : pv;
      pv = (m == 2) ? p2 : pv;
      pv = (m == 3) ? p3 : pv;
      if (m < 4) sc2[c * 16 + q * 4 + m][wave] = pv;
    }
    // online accumulate of the PREVIOUS chunk (other buffer)
    if (c > 0) accum(bufc ^ 1, (c - 1) * CHUNK);
    __syncthreads();  // B2: accum reads done before next stage overwrites
  }

  // tail: accumulate the last chunk (sc2 visible via loop-end B2)
  accum((nchunks - 1) & 1, (nchunks - 1) * CHUNK);
  if (lane == 0) den8[wave] = den;   // den uniform across lanes of a wave
  __syncthreads();

  const float denom = den8[0] + den8[1] + den8[2] + den8[3] +
                      den8[4] + den8[5] + den8[6] + den8[7];
  const float scale = args.coef[a] / denom;

  // cross-wave reduce of pA/pB, one atomic per column
  const int g = tid >> 3, rr = tid & 7;
  const float* cp = (rr < 4) ? &pA[0][g * 4 + rr] : &pB[0][g * 4 + (rr - 4)];
  float val = 0.f;
  #pragma unroll
  for (int w = 0; w < 8; ++w) val += cp[w * 256];
  atomicAdd(&out[(size_t)b * DD + tid], val * scale);
}

extern "C" void kernel_launch(void* const* d_in, const int* in_sizes, int n_in,
                              void* d_out, int out_size, void* d_ws, size_t ws_size,
                              hipStream_t stream) {
  AttendArgs args;
  args.feats[0] = (const float*)d_in[0];
  args.wfeat[0] = (const float*)d_in[4];
  args.wf[0]    = (const float*)d_in[6];          // vec_first=False: wf = w_p[:100]
  args.bias[0]  = (const float*)d_in[7];
  args.N[0] = 196; args.coef[0] = 1.0f;

  args.feats[1] = (const float*)d_in[1];
  args.wfeat[1] = (const float*)d_in[9];
  args.wf[1]    = (const float*)d_in[10] + 100;   // vec_first=True: wf = w_p[100:]
  args.bias[1]  = (const float*)d_in[11];
  args.N[1] = 200; args.coef[1] = 1.0f;

  args.feats[2] = (const float*)d_in[2];
  args.wfeat[2] = (const float*)d_in[13];
  args.wf[2]    = (const float*)d_in[14] + 100;
  args.bias[2]  = (const float*)d_in[15];
  args.N[2] = 200; args.coef[2] = 0.5f;

  args.feats[3] = (const float*)d_in[3];
  args.wfeat[3] = (const float*)d_in[17];
  args.wf[3]    = (const float*)d_in[18] + 100;
  args.bias[3]  = (const float*)d_in[19];
  args.N[3] = 50;  args.coef[3] = 0.5f;

  hipMemsetAsync(d_out, 0, (size_t)out_size * sizeof(float), stream);
  fused_kernel<<<dim3(4 * 256), dim3(512), 0, stream>>>(args, (float*)d_out);
}

// Round 3
// 350.688 us; speedup vs baseline: 1.2823x; 1.2823x over previous
//
#include <hip/hip_runtime.h>

#define DD 512
#define DKk 100
#define NT 7          // ceil(100/16) column tiles
#define CHUNK 16
#define MAXN 208      // max padded N (200 -> 13 chunks * 16)
#define LDS_STRIDE 520  // shorts per staged row (+8 pad)

typedef __attribute__((ext_vector_type(8))) short short8;
typedef __attribute__((ext_vector_type(4))) float f32x4;

struct AttendArgs {
  const float* feats[4];
  const float* wfeat[4];
  const float* wf[4];
  const float* bias[4];
  int   N[4];
  float coef[4];
};

// fp32 -> bf16 bits, round-to-nearest-even
__device__ __forceinline__ short f2bf(float x) {
  unsigned u = __builtin_bit_cast(unsigned, x);
  unsigned r = (u + 0x7fffu + ((u >> 16) & 1u)) >> 16;
  return (short)r;
}
__device__ __forceinline__ float bf2f(unsigned short s) {
  unsigned u = ((unsigned)s) << 16;
  return __builtin_bit_cast(float, u);
}
__device__ __forceinline__ float fast_tanh(float x) {
  const float e = __expf(2.0f * x);
  return 1.0f - 2.0f / (e + 1.0f);
}

// VALU cross-lane add via DPP (row = 16 lanes). xor1, xor2, half_mirror,
// mirror = full 16-lane sum. (Correctness verified in R2's passing run.)
#define DPP_ADD(x, CTRL)                                                      \
  (x) += __builtin_bit_cast(float, __builtin_amdgcn_update_dpp(               \
             0, __builtin_bit_cast(int, (x)), (CTRL), 0xF, 0xF, true))

// ---------------------------------------------------------------------------
// wprep (coalesced, restored from R1): stage 128 rows of w into LDS with
// linear coalesced loads, then emit MFMA-B-fragment order.
// Layout: wfrag[((a*7+t)*16+ks)*512 + lane*8 + j] = bf16(w[d][col]),
// d = ks*32 + (lane>>4)*8 + j, col = t*16 + (lane&15). Zero past col>=100.
// ---------------------------------------------------------------------------
__global__ void wprep_kernel(AttendArgs args, unsigned short* __restrict__ wfrag) {
  const int a   = blockIdx.x >> 2;
  const int qtr = blockIdx.x & 3;
  const int tid = threadIdx.x;
  const int lane = tid & 63;
  const int m = lane & 15;
  const int q = lane >> 4;
  const int sub = tid >> 6;             // 0..3
  const int ks  = qtr * 4 + sub;
  __shared__ float wbuf[128 * DKk];     // 51,200 B
  const float* __restrict__ w = args.wfeat[a] + (size_t)qtr * 128 * DKk;
  #pragma unroll
  for (int i = 0; i < 50; ++i)          // 128*100 = 50*256 floats, coalesced
    wbuf[i * 256 + tid] = w[i * 256 + tid];
  __syncthreads();
  #pragma unroll
  for (int t = 0; t < NT; ++t) {
    const int col = t * 16 + m;
    short8 v;
    #pragma unroll
    for (int j = 0; j < 8; ++j) {
      const int drel = sub * 32 + q * 8 + j;     // d - qtr*128
      v[j] = (col < DKk) ? f2bf(wbuf[drel * DKk + col]) : (short)0;
    }
    unsigned short* dst = wfrag + (size_t)(((a * NT + t) * 16 + ks) * 512) + lane * 8;
    *reinterpret_cast<short8*>(dst) = v;
  }
}

// ---------------------------------------------------------------------------
// Fused per-(a,b) kernel, R3.
// Occupancy thesis: R1 needed 132 unified regs -> 8 waves/CU. Honest cuts
// (shared-exp phase + serialized accum + wprep-restored prologue) target
// peak <= 128 WITHOUT __launch_bounds__ forcing (R2's force -> 80MB spills).
// Per chunk (2 barriers):
//   stage(c) -> [wave7: ex[r]=exp(sum sc2(c-1 rows))] -> prefetch(c+1) -> B1
//   -> [waves 0-6: MFMA(c)+tanh+DPP -> sc2(c)] [all: accum(c-1) via ex] -> B2
// accum reads 2 broadcast floats (ex[wave], ex[wave+8]) instead of 4xf32x4
// score vectors + 2 exp per thread: ~-14 peak regs, -26 VALU/thread/chunk.
// Softmax: scores bounded (|s| <~ 4) => no max pass; padded rows have
// sc2[n][7] = -1e30 so ex -> 0 exactly.
// ---------------------------------------------------------------------------
__global__ __launch_bounds__(512)
void fused_kernel(AttendArgs args, const unsigned short* __restrict__ wfrag,
                  float* __restrict__ out) {
  const int a = blockIdx.x & 3;        // interleave a for load balance
  const int b = blockIdx.x >> 2;
  const int tid = threadIdx.x;
  const int lane = tid & 63;
  const int wave = tid >> 6;           // col tile t (0..6 MFMA; all 8 accum)
  const int m = lane & 15;
  const int q = lane >> 4;
  const int N = args.N[a];
  const float* __restrict__ feats = args.feats[a] + (size_t)b * (size_t)N * DD;

  __shared__ __align__(16) unsigned short f_lds[2][CHUNK][LDS_STRIDE]; // 33,280
  __shared__ __align__(16) float sc2[MAXN][8];                         //  6,656
  __shared__ __align__(16) float pA[8][256];                           //  8,192
  __shared__ __align__(16) float pB[8][256];                           //  8,192
  __shared__ float ex[16];
  __shared__ float den8[8];
  // total ~56.5 KB static; 2 blocks/CU = 113 KB <= 160 KiB.

  // --- B fragments from pre-formatted wfrag (16 clean b128 loads, L2-hot) ---
  short8 bfrag[16];
  float wfv = 0.f;
  if (wave < NT) {
    const int col = wave * 16 + m;
    wfv = (col < DKk) ? args.wf[a][col] : 0.f;
    const unsigned short* src = wfrag + (size_t)((a * NT + wave) * 16) * 512 + lane * 8;
    #pragma unroll
    for (int ks = 0; ks < 16; ++ks)
      bfrag[ks] = *reinterpret_cast<const short8*>(src + (size_t)ks * 512);
  } else {
    #pragma unroll
    for (int ks = 0; ks < 16; ++ks) bfrag[ks] = short8(0);
  }

  // bias in score slot 7; -1e30 sentinel kills padded rows in exp()
  if (tid < MAXN) sc2[tid][7] = (tid < N) ? args.bias[a][tid] : -1e30f;
  {
    const f32x4 z = {0.f, 0.f, 0.f, 0.f};
    *reinterpret_cast<f32x4*>(&pA[wave][lane * 4]) = z;
    *reinterpret_cast<f32x4*>(&pB[wave][lane * 4]) = z;
  }

  const int nchunks = (N + CHUNK - 1) / CHUNK;
  float den = 0.f;

  // accumulate chunk staged in f_lds[pb]; per-row exp already in ex[0..15].
  // Thread (wave, lane) owns cols [lane*8, lane*8+8), rows {wave, wave+8}.
  // Serialized halves to cap transient register pressure.
  auto accum = [&](int pb) {
    const float e1 = ex[wave];          // LDS broadcast (uniform per wave)
    const float e2 = ex[wave + 8];
    den += e1 + e2;
    f32x4 lo = *reinterpret_cast<const f32x4*>(&pA[wave][lane * 4]);
    f32x4 hi = *reinterpret_cast<const f32x4*>(&pB[wave][lane * 4]);
    {
      const short8 f1 = *reinterpret_cast<const short8*>(&f_lds[pb][wave][lane * 8]);
      #pragma unroll
      for (int j = 0; j < 4; ++j) {
        lo[j] = fmaf(e1, bf2f((unsigned short)f1[j]),     lo[j]);
        hi[j] = fmaf(e1, bf2f((unsigned short)f1[j + 4]), hi[j]);
      }
    }
    {
      const short8 f2 = *reinterpret_cast<const short8*>(&f_lds[pb][wave + 8][lane * 8]);
      #pragma unroll
      for (int j = 0; j < 4; ++j) {
        lo[j] = fmaf(e2, bf2f((unsigned short)f2[j]),     lo[j]);
        hi[j] = fmaf(e2, bf2f((unsigned short)f2[j + 4]), hi[j]);
      }
    }
    *reinterpret_cast<f32x4*>(&pA[wave][lane * 4]) = lo;
    *reinterpret_cast<f32x4*>(&pB[wave][lane * 4]) = hi;
  };

  // --- prefetch chunk 0: thread loads rows {wave, wave+8}, 32B each ---------
  float4 pf[4];
  #pragma unroll
  for (int h = 0; h < 2; ++h) {
    const int row = wave + h * 8;
    const float* src = feats + (size_t)row * DD + lane * 8;
    const bool ok = row < N;
    pf[2 * h]     = ok ? *reinterpret_cast<const float4*>(src)     : make_float4(0.f, 0.f, 0.f, 0.f);
    pf[2 * h + 1] = ok ? *reinterpret_cast<const float4*>(src + 4) : make_float4(0.f, 0.f, 0.f, 0.f);
  }

  for (int c = 0; c < nchunks; ++c) {
    const int bufc = c & 1;
    // stage regs (chunk c) -> bf16 LDS, one 16B write per row-half
    #pragma unroll
    for (int h = 0; h < 2; ++h) {
      const float4 va = pf[2 * h], vb = pf[2 * h + 1];
      short8 pk = { f2bf(va.x), f2bf(va.y), f2bf(va.z), f2bf(va.w),
                    f2bf(vb.x), f2bf(vb.y), f2bf(vb.z), f2bf(vb.w) };
      *reinterpret_cast<short8*>(&f_lds[bufc][wave + h * 8][lane * 8]) = pk;
    }
    // wave 7 (idle in MFMA phase): per-row exp of chunk c-1 (16 rows).
    // sc2(c-1) synced at B2(c-1); readers of ex start after B1 below.
    if (wave == 7 && c > 0 && lane < 16) {
      const int row = (c - 1) * CHUNK + lane;
      const f32x4 s0 = *reinterpret_cast<const f32x4*>(&sc2[row][0]);
      const f32x4 s1 = *reinterpret_cast<const f32x4*>(&sc2[row][4]);
      ex[lane] = __expf(s0[0] + s0[1] + s0[2] + s0[3] +
                        s1[0] + s1[1] + s1[2] + s1[3]);
    }
    // issue prefetch of chunk c+1 (stays in flight across B1+compute+B2)
    if (c + 1 < nchunks) {
      const int n0n = (c + 1) * CHUNK;
      #pragma unroll
      for (int h = 0; h < 2; ++h) {
        const int row = n0n + wave + h * 8;
        const float* src = feats + (size_t)row * DD + lane * 8;
        const bool ok = row < N;
        pf[2 * h]     = ok ? *reinterpret_cast<const float4*>(src)     : make_float4(0.f, 0.f, 0.f, 0.f);
        pf[2 * h + 1] = ok ? *reinterpret_cast<const float4*>(src + 4) : make_float4(0.f, 0.f, 0.f, 0.f);
      }
    }
    __syncthreads();  // B1: staging of c + ex(c-1) visible

    if (wave < NT) {
      f32x4 acc = {0.f, 0.f, 0.f, 0.f};
      #pragma unroll
      for (int ks = 0; ks < 16; ++ks) {
        const short8 af = *reinterpret_cast<const short8*>(&f_lds[bufc][m][ks * 32 + q * 8]);
        acc = __builtin_amdgcn_mfma_f32_16x16x32_bf16(af, bfrag[ks], acc, 0, 0, 0);
      }
      float p0 = fast_tanh(acc[0]) * wfv;
      float p1 = fast_tanh(acc[1]) * wfv;
      float p2 = fast_tanh(acc[2]) * wfv;
      float p3 = fast_tanh(acc[3]) * wfv;
      DPP_ADD(p0, 0xB1);  DPP_ADD(p1, 0xB1);  DPP_ADD(p2, 0xB1);  DPP_ADD(p3, 0xB1);
      DPP_ADD(p0, 0x4E);  DPP_ADD(p1, 0x4E);  DPP_ADD(p2, 0x4E);  DPP_ADD(p3, 0x4E);
      DPP_ADD(p0, 0x141); DPP_ADD(p1, 0x141); DPP_ADD(p2, 0x141); DPP_ADD(p3, 0x141);
      DPP_ADD(p0, 0x140); DPP_ADD(p1, 0x140); DPP_ADD(p2, 0x140); DPP_ADD(p3, 0x140);
      // lanes m=0..3 write rows q*4+m (static indices via select chain)
      float pv = p0;
      pv = (m == 1) ? p1 : pv;
      pv = (m == 2) ? p2 : pv;
      pv = (m == 3) ? p3 : pv;
      if (m < 4) sc2[c * 16 + q * 4 + m][wave] = pv;
    }
    // online accumulate of the PREVIOUS chunk (other buffer)
    if (c > 0) accum(bufc ^ 1);
    __syncthreads();  // B2: accum reads done before next stage overwrites
  }

  // tail: ex + accum for the last chunk
  if (wave == 7 && lane < 16) {
    const int row = (nchunks - 1) * CHUNK + lane;
    const f32x4 s0 = *reinterpret_cast<const f32x4*>(&sc2[row][0]);
    const f32x4 s1 = *reinterpret_cast<const f32x4*>(&sc2[row][4]);
    ex[lane] = __expf(s0[0] + s0[1] + s0[2] + s0[3] +
                      s1[0] + s1[1] + s1[2] + s1[3]);
  }
  __syncthreads();
  accum((nchunks - 1) & 1);
  if (lane == 0) den8[wave] = den;   // den uniform across lanes of a wave
  __syncthreads();

  const float denom = den8[0] + den8[1] + den8[2] + den8[3] +
                      den8[4] + den8[5] + den8[6] + den8[7];
  const float scale = args.coef[a] / denom;

  // cross-wave reduce of pA/pB, one atomic per column
  const int g = tid >> 3, rr = tid & 7;
  const float* cp = (rr < 4) ? &pA[0][g * 4 + rr] : &pB[0][g * 4 + (rr - 4)];
  float val = 0.f;
  #pragma unroll
  for (int w = 0; w < 8; ++w) val += cp[w * 256];
  atomicAdd(&out[(size_t)b * DD + tid], val * scale);
}

extern "C" void kernel_launch(void* const* d_in, const int* in_sizes, int n_in,
                              void* d_out, int out_size, void* d_ws, size_t ws_size,
                              hipStream_t stream) {
  AttendArgs args;
  args.feats[0] = (const float*)d_in[0];
  args.wfeat[0] = (const float*)d_in[4];
  args.wf[0]    = (const float*)d_in[6];          // vec_first=False: wf = w_p[:100]
  args.bias[0]  = (const float*)d_in[7];
  args.N[0] = 196; args.coef[0] = 1.0f;

  args.feats[1] = (const float*)d_in[1];
  args.wfeat[1] = (const float*)d_in[9];
  args.wf[1]    = (const float*)d_in[10] + 100;   // vec_first=True: wf = w_p[100:]
  args.bias[1]  = (const float*)d_in[11];
  args.N[1] = 200; args.coef[1] = 1.0f;

  args.feats[2] = (const float*)d_in[2];
  args.wfeat[2] = (const float*)d_in[13];
  args.wf[2]    = (const float*)d_in[14] + 100;
  args.bias[2]  = (const float*)d_in[15];
  args.N[2] = 200; args.coef[2] = 0.5f;

  args.feats[3] = (const float*)d_in[3];
  args.wfeat[3] = (const float*)d_in[17];
  args.wf[3]    = (const float*)d_in[18] + 100;
  args.bias[3]  = (const float*)d_in[19];
  args.N[3] = 50;  args.coef[3] = 0.5f;

  unsigned short* wfrag = (unsigned short*)d_ws;  // 4*7*16*512*2 = 458,752 B

  hipMemsetAsync(d_out, 0, (size_t)out_size * sizeof(float), stream);
  wprep_kernel<<<dim3(16), dim3(256), 0, stream>>>(args, wfrag);
  fused_kernel<<<dim3(4 * 256), dim3(512), 0, stream>>>(args, wfrag, (float*)d_out);
}

// Round 4
// 349.132 us; speedup vs baseline: 1.2880x; 1.0045x over previous
//
#include <hip/hip_runtime.h>

#define DD 512
#define DKk 100
#define NT 7          // ceil(100/16) column tiles
#define CHUNK 16
#define MAXN 208      // max padded N (200 -> 13 chunks * 16)
#define LDS_STRIDE 520  // shorts per staged row (+8 pad)

typedef __attribute__((ext_vector_type(8))) short short8;
typedef __attribute__((ext_vector_type(4))) float f32x4;

struct AttendArgs {
  const float* feats[4];
  const float* wfeat[4];
  const float* wf[4];
  const float* bias[4];
  int   N[4];
  float coef[4];
};

// fp32 -> bf16 bits, round-to-nearest-even
__device__ __forceinline__ short f2bf(float x) {
  unsigned u = __builtin_bit_cast(unsigned, x);
  unsigned r = (u + 0x7fffu + ((u >> 16) & 1u)) >> 16;
  return (short)r;
}
__device__ __forceinline__ float bf2f(unsigned short s) {
  unsigned u = ((unsigned)s) << 16;
  return __builtin_bit_cast(float, u);
}
__device__ __forceinline__ float fast_tanh(float x) {
  const float e = __expf(2.0f * x);
  return 1.0f - 2.0f / (e + 1.0f);
}

// Raw workgroup barrier that drains ONLY LDS ops (lgkmcnt), leaving global
// loads in flight across the barrier. __syncthreads() would emit
// s_waitcnt vmcnt(0) before s_barrier (HIP memory-legalizer), serializing our
// register prefetch against HBM latency every chunk — the R3 bottleneck.
// Single asm with "memory" clobber = two-sided compiler memory fence, so LDS
// writes can't sink below it and LDS reads can't hoist above it (rule-18 safe:
// MFMA's LDS source loads are memory ops, ordered by the clobber).
__device__ __forceinline__ void barrier_lgkm_only() {
  asm volatile("s_waitcnt lgkmcnt(0)\n\ts_barrier" ::: "memory");
}

// VALU cross-lane add via DPP (row = 16 lanes). xor1, xor2, half_mirror,
// mirror = full 16-lane sum. (Correctness verified in R2/R3 passing runs.)
#define DPP_ADD(x, CTRL)                                                      \
  (x) += __builtin_bit_cast(float, __builtin_amdgcn_update_dpp(               \
             0, __builtin_bit_cast(int, (x)), (CTRL), 0xF, 0xF, true))

// ---------------------------------------------------------------------------
// wprep (coalesced): stage 128 rows of w into LDS with linear coalesced
// loads, then emit MFMA-B-fragment order.
// Layout: wfrag[((a*7+t)*16+ks)*512 + lane*8 + j] = bf16(w[d][col]),
// d = ks*32 + (lane>>4)*8 + j, col = t*16 + (lane&15). Zero past col>=100.
// ---------------------------------------------------------------------------
__global__ void wprep_kernel(AttendArgs args, unsigned short* __restrict__ wfrag) {
  const int a   = blockIdx.x >> 2;
  const int qtr = blockIdx.x & 3;
  const int tid = threadIdx.x;
  const int lane = tid & 63;
  const int m = lane & 15;
  const int q = lane >> 4;
  const int sub = tid >> 6;             // 0..3
  const int ks  = qtr * 4 + sub;
  __shared__ float wbuf[128 * DKk];     // 51,200 B
  const float* __restrict__ w = args.wfeat[a] + (size_t)qtr * 128 * DKk;
  #pragma unroll
  for (int i = 0; i < 50; ++i)          // 128*100 = 50*256 floats, coalesced
    wbuf[i * 256 + tid] = w[i * 256 + tid];
  __syncthreads();
  #pragma unroll
  for (int t = 0; t < NT; ++t) {
    const int col = t * 16 + m;
    short8 v;
    #pragma unroll
    for (int j = 0; j < 8; ++j) {
      const int drel = sub * 32 + q * 8 + j;     // d - qtr*128
      v[j] = (col < DKk) ? f2bf(wbuf[drel * DKk + col]) : (short)0;
    }
    unsigned short* dst = wfrag + (size_t)(((a * NT + t) * 16 + ks) * 512) + lane * 8;
    *reinterpret_cast<short8*>(dst) = v;
  }
}

// ---------------------------------------------------------------------------
// Fused per-(a,b) kernel, R4.
// R3 landed 2 blocks/CU, no spills (VGPR 64 + AGPR 64 = 128 unified), 130us.
// R4 changes ONE thing: in-loop barriers -> lgkmcnt-only (see barrier_lgkm_only)
// so the chunk c+1 register prefetch truly stays in flight across
// B1 + MFMA/accum + B2, instead of being drained by __syncthreads' implicit
// vmcnt(0) at every barrier (26 serial ~900cy HBM latencies per block in R3).
// Per chunk:
//   stage(c) -> [wave7: ex(c-1)] -> prefetch(c+1) -> B1 ->
//   [waves 0-6: MFMA(c)+tanh+DPP -> sc2(c)] [all: accum(c-1) via ex] -> B2
// Softmax: scores bounded (|s| <~ 4) => no max pass; padded rows have
// sc2[n][7] = -1e30 so ex -> 0 exactly.
// ---------------------------------------------------------------------------
__global__ __launch_bounds__(512)
void fused_kernel(AttendArgs args, const unsigned short* __restrict__ wfrag,
                  float* __restrict__ out) {
  const int a = blockIdx.x & 3;        // interleave a for load balance
  const int b = blockIdx.x >> 2;
  const int tid = threadIdx.x;
  const int lane = tid & 63;
  const int wave = tid >> 6;           // col tile t (0..6 MFMA; all 8 accum)
  const int m = lane & 15;
  const int q = lane >> 4;
  const int N = args.N[a];
  const float* __restrict__ feats = args.feats[a] + (size_t)b * (size_t)N * DD;

  __shared__ __align__(16) unsigned short f_lds[2][CHUNK][LDS_STRIDE]; // 33,280
  __shared__ __align__(16) float sc2[MAXN][8];                         //  6,656
  __shared__ __align__(16) float pA[8][256];                           //  8,192
  __shared__ __align__(16) float pB[8][256];                           //  8,192
  __shared__ float ex[16];
  __shared__ float den8[8];
  // total ~56.5 KB static; 2 blocks/CU = 113 KB <= 160 KiB.

  // --- B fragments from pre-formatted wfrag (16 clean b128 loads, L2-hot) ---
  short8 bfrag[16];
  float wfv = 0.f;
  if (wave < NT) {
    const int col = wave * 16 + m;
    wfv = (col < DKk) ? args.wf[a][col] : 0.f;
    const unsigned short* src = wfrag + (size_t)((a * NT + wave) * 16) * 512 + lane * 8;
    #pragma unroll
    for (int ks = 0; ks < 16; ++ks)
      bfrag[ks] = *reinterpret_cast<const short8*>(src + (size_t)ks * 512);
  } else {
    #pragma unroll
    for (int ks = 0; ks < 16; ++ks) bfrag[ks] = short8(0);
  }

  // bias in score slot 7; -1e30 sentinel kills padded rows in exp()
  if (tid < MAXN) sc2[tid][7] = (tid < N) ? args.bias[a][tid] : -1e30f;
  {
    const f32x4 z = {0.f, 0.f, 0.f, 0.f};
    *reinterpret_cast<f32x4*>(&pA[wave][lane * 4]) = z;
    *reinterpret_cast<f32x4*>(&pB[wave][lane * 4]) = z;
  }

  const int nchunks = (N + CHUNK - 1) / CHUNK;
  float den = 0.f;

  // accumulate chunk staged in f_lds[pb]; per-row exp already in ex[0..15].
  // Thread (wave, lane) owns cols [lane*8, lane*8+8), rows {wave, wave+8}.
  // Serialized halves to cap transient register pressure.
  auto accum = [&](int pb) {
    const float e1 = ex[wave];          // LDS broadcast (uniform per wave)
    const float e2 = ex[wave + 8];
    den += e1 + e2;
    f32x4 lo = *reinterpret_cast<const f32x4*>(&pA[wave][lane * 4]);
    f32x4 hi = *reinterpret_cast<const f32x4*>(&pB[wave][lane * 4]);
    {
      const short8 f1 = *reinterpret_cast<const short8*>(&f_lds[pb][wave][lane * 8]);
      #pragma unroll
      for (int j = 0; j < 4; ++j) {
        lo[j] = fmaf(e1, bf2f((unsigned short)f1[j]),     lo[j]);
        hi[j] = fmaf(e1, bf2f((unsigned short)f1[j + 4]), hi[j]);
      }
    }
    {
      const short8 f2 = *reinterpret_cast<const short8*>(&f_lds[pb][wave + 8][lane * 8]);
      #pragma unroll
      for (int j = 0; j < 4; ++j) {
        lo[j] = fmaf(e2, bf2f((unsigned short)f2[j]),     lo[j]);
        hi[j] = fmaf(e2, bf2f((unsigned short)f2[j + 4]), hi[j]);
      }
    }
    *reinterpret_cast<f32x4*>(&pA[wave][lane * 4]) = lo;
    *reinterpret_cast<f32x4*>(&pB[wave][lane * 4]) = hi;
  };

  // --- prefetch chunk 0: thread loads rows {wave, wave+8}, 32B each ---------
  float4 pf[4];
  #pragma unroll
  for (int h = 0; h < 2; ++h) {
    const int row = wave + h * 8;
    const float* src = feats + (size_t)row * DD + lane * 8;
    const bool ok = row < N;
    pf[2 * h]     = ok ? *reinterpret_cast<const float4*>(src)     : make_float4(0.f, 0.f, 0.f, 0.f);
    pf[2 * h + 1] = ok ? *reinterpret_cast<const float4*>(src + 4) : make_float4(0.f, 0.f, 0.f, 0.f);
  }

  for (int c = 0; c < nchunks; ++c) {
    const int bufc = c & 1;
    // stage regs (chunk c) -> bf16 LDS, one 16B write per row-half
    #pragma unroll
    for (int h = 0; h < 2; ++h) {
      const float4 va = pf[2 * h], vb = pf[2 * h + 1];
      short8 pk = { f2bf(va.x), f2bf(va.y), f2bf(va.z), f2bf(va.w),
                    f2bf(vb.x), f2bf(vb.y), f2bf(vb.z), f2bf(vb.w) };
      *reinterpret_cast<short8*>(&f_lds[bufc][wave + h * 8][lane * 8]) = pk;
    }
    // wave 7 (idle in MFMA phase): per-row exp of chunk c-1 (16 rows).
    if (wave == 7 && c > 0 && lane < 16) {
      const int row = (c - 1) * CHUNK + lane;
      const f32x4 s0 = *reinterpret_cast<const f32x4*>(&sc2[row][0]);
      const f32x4 s1 = *reinterpret_cast<const f32x4*>(&sc2[row][4]);
      ex[lane] = __expf(s0[0] + s0[1] + s0[2] + s0[3] +
                        s1[0] + s1[1] + s1[2] + s1[3]);
    }
    // issue prefetch of chunk c+1 (NOW genuinely in flight across both
    // barriers: the lgkm-only barrier does not drain vmcnt; the compiler's
    // vmcnt wait lands at the stage step of the next iteration)
    if (c + 1 < nchunks) {
      const int n0n = (c + 1) * CHUNK;
      #pragma unroll
      for (int h = 0; h < 2; ++h) {
        const int row = n0n + wave + h * 8;
        const float* src = feats + (size_t)row * DD + lane * 8;
        const bool ok = row < N;
        pf[2 * h]     = ok ? *reinterpret_cast<const float4*>(src)     : make_float4(0.f, 0.f, 0.f, 0.f);
        pf[2 * h + 1] = ok ? *reinterpret_cast<const float4*>(src + 4) : make_float4(0.f, 0.f, 0.f, 0.f);
      }
    }
    barrier_lgkm_only();  // B1: staging of c + ex(c-1) visible (LDS only)

    if (wave < NT) {
      f32x4 acc = {0.f, 0.f, 0.f, 0.f};
      #pragma unroll
      for (int ks = 0; ks < 16; ++ks) {
        const short8 af = *reinterpret_cast<const short8*>(&f_lds[bufc][m][ks * 32 + q * 8]);
        acc = __builtin_amdgcn_mfma_f32_16x16x32_bf16(af, bfrag[ks], acc, 0, 0, 0);
      }
      float p0 = fast_tanh(acc[0]) * wfv;
      float p1 = fast_tanh(acc[1]) * wfv;
      float p2 = fast_tanh(acc[2]) * wfv;
      float p3 = fast_tanh(acc[3]) * wfv;
      DPP_ADD(p0, 0xB1);  DPP_ADD(p1, 0xB1);  DPP_ADD(p2, 0xB1);  DPP_ADD(p3, 0xB1);
      DPP_ADD(p0, 0x4E);  DPP_ADD(p1, 0x4E);  DPP_ADD(p2, 0x4E);  DPP_ADD(p3, 0x4E);
      DPP_ADD(p0, 0x141); DPP_ADD(p1, 0x141); DPP_ADD(p2, 0x141); DPP_ADD(p3, 0x141);
      DPP_ADD(p0, 0x140); DPP_ADD(p1, 0x140); DPP_ADD(p2, 0x140); DPP_ADD(p3, 0x140);
      // lanes m=0..3 write rows q*4+m (static indices via select chain)
      float pv = p0;
      pv = (m == 1) ? p1 : pv;
      pv = (m == 2) ? p2 : pv;
      pv = (m == 3) ? p3 : pv;
      if (m < 4) sc2[c * 16 + q * 4 + m][wave] = pv;
    }
    // online accumulate of the PREVIOUS chunk (other buffer)
    if (c > 0) accum(bufc ^ 1);
    barrier_lgkm_only();  // B2: accum reads done before next stage overwrites
  }

  // tail: ex + accum for the last chunk
  if (wave == 7 && lane < 16) {
    const int row = (nchunks - 1) * CHUNK + lane;
    const f32x4 s0 = *reinterpret_cast<const f32x4*>(&sc2[row][0]);
    const f32x4 s1 = *reinterpret_cast<const f32x4*>(&sc2[row][4]);
    ex[lane] = __expf(s0[0] + s0[1] + s0[2] + s0[3] +
                      s1[0] + s1[1] + s1[2] + s1[3]);
  }
  __syncthreads();
  accum((nchunks - 1) & 1);
  if (lane == 0) den8[wave] = den;   // den uniform across lanes of a wave
  __syncthreads();

  const float denom = den8[0] + den8[1] + den8[2] + den8[3] +
                      den8[4] + den8[5] + den8[6] + den8[7];
  const float scale = args.coef[a] / denom;

  // cross-wave reduce of pA/pB, one atomic per column
  const int g = tid >> 3, rr = tid & 7;
  const float* cp = (rr < 4) ? &pA[0][g * 4 + rr] : &pB[0][g * 4 + (rr - 4)];
  float val = 0.f;
  #pragma unroll
  for (int w = 0; w < 8; ++w) val += cp[w * 256];
  atomicAdd(&out[(size_t)b * DD + tid], val * scale);
}

extern "C" void kernel_launch(void* const* d_in, const int* in_sizes, int n_in,
                              void* d_out, int out_size, void* d_ws, size_t ws_size,
                              hipStream_t stream) {
  AttendArgs args;
  args.feats[0] = (const float*)d_in[0];
  args.wfeat[0] = (const float*)d_in[4];
  args.wf[0]    = (const float*)d_in[6];          // vec_first=False: wf = w_p[:100]
  args.bias[0]  = (const float*)d_in[7];
  args.N[0] = 196; args.coef[0] = 1.0f;

  args.feats[1] = (const float*)d_in[1];
  args.wfeat[1] = (const float*)d_in[9];
  args.wf[1]    = (const float*)d_in[10] + 100;   // vec_first=True: wf = w_p[100:]
  args.bias[1]  = (const float*)d_in[11];
  args.N[1] = 200; args.coef[1] = 1.0f;

  args.feats[2] = (const float*)d_in[2];
  args.wfeat[2] = (const float*)d_in[13];
  args.wf[2]    = (const float*)d_in[14] + 100;
  args.bias[2]  = (const float*)d_in[15];
  args.N[2] = 200; args.coef[2] = 0.5f;

  args.feats[3] = (const float*)d_in[3];
  args.wfeat[3] = (const float*)d_in[17];
  args.wf[3]    = (const float*)d_in[18] + 100;
  args.bias[3]  = (const float*)d_in[19];
  args.N[3] = 50;  args.coef[3] = 0.5f;

  unsigned short* wfrag = (unsigned short*)d_ws;  // 4*7*16*512*2 = 458,752 B

  hipMemsetAsync(d_out, 0, (size_t)out_size * sizeof(float), stream);
  wprep_kernel<<<dim3(16), dim3(256), 0, stream>>>(args, wfrag);
  fused_kernel<<<dim3(4 * 256), dim3(512), 0, stream>>>(args, wfrag, (float*)d_out);
}